// Round 7
// baseline (530.283 us; speedup 1.0000x reference)
//
#include <hip/hip_runtime.h>
#include <hip/hip_bf16.h>

#define EPS 1e-5f
#define SCH 512          // scan chunk = 256 threads x 2 elems
#define PB_CH 2048       // edges per block in k_pairs
typedef __hip_bfloat16 bf16;
typedef int iv4 __attribute__((ext_vector_type(4)));
typedef int iv2 __attribute__((ext_vector_type(2)));

// slice = floor(d / ceil(N/8)) via magic multiply (M = ceil(2^32/ss), exact for d*ss < 2^32)
__device__ __forceinline__ int slice_of(int d, unsigned M) {
    return (int)(((unsigned long long)(unsigned)d * M) >> 32);
}

// ---------------------------------------------------------------------------
// Phase A: 8-bin histogram of dst (read once). LDS 8x8 replicated counters.
// ---------------------------------------------------------------------------
__global__ void k_hist(const int* __restrict__ dst, int* __restrict__ binCnt,
                       unsigned M, int nE)
{
    __shared__ int hist[8][8];
    int t = threadIdx.x;
    if (t < 64) hist[t >> 3][t & 7] = 0;
    __syncthreads();
    int r = t & 7;
    int tid = blockIdx.x * blockDim.x + t;
    int stride = gridDim.x * blockDim.x;
    const iv4* dst4 = (const iv4*)dst;
    int nE4 = nE >> 2;
    for (int e = tid; e < nE4; e += stride) {
        iv4 d = __builtin_nontemporal_load(&dst4[e]);
        atomicAdd(&hist[slice_of(d.x, M)][r], 1);
        atomicAdd(&hist[slice_of(d.y, M)][r], 1);
        atomicAdd(&hist[slice_of(d.z, M)][r], 1);
        atomicAdd(&hist[slice_of(d.w, M)][r], 1);
    }
    if (blockIdx.x == 0 && t == 0) {      // tail (nE % 4)
        for (int e = nE4 << 2; e < nE; ++e)
            atomicAdd(&hist[slice_of(dst[e], M)][0], 1);
    }
    __syncthreads();
    if (t < 8) {
        int tot = 0;
#pragma unroll
        for (int k = 0; k < 8; ++k) tot += hist[t][k];
        if (tot) atomicAdd(&binCnt[t * 32], tot);
    }
}

// ---------------------------------------------------------------------------
// Tiny: exclusive scan of 8 bin counts -> binStart[9], init binCur
// ---------------------------------------------------------------------------
__global__ void k_binscan(const int* __restrict__ binCnt, int* __restrict__ binStart,
                          int* __restrict__ binCur)
{
    if (threadIdx.x == 0) {
        int run = 0;
        for (int b = 0; b < 8; ++b) {
            binStart[b] = run;
            binCur[b * 32] = run;
            run += binCnt[b * 32];
        }
        binStart[8] = run;
    }
}

// ---------------------------------------------------------------------------
// Phase B: partition edges into bin-contiguous (dst,src) staging pairs.
// Per block: LDS histogram of its 2048-edge chunk, one global reservation
// per bin, per-(bin,replica) sub-bases, then scatter-write pairs (nt).
// ---------------------------------------------------------------------------
__global__ void k_pairs(const int* __restrict__ src, const int* __restrict__ dst,
                        int* __restrict__ binCur, iv2* __restrict__ stg,
                        unsigned M, int nE)
{
    __shared__ int hist[8][8], base[8][8], cur[8][8];
    int t = threadIdx.x;
    if (t < 64) { hist[t >> 3][t & 7] = 0; cur[t >> 3][t & 7] = 0; }
    __syncthreads();
    int r = t & 7;
    const iv4* dst4 = (const iv4*)dst;
    const iv4* src4 = (const iv4*)src;
    int nE4 = nE >> 2;
    int i0 = blockIdx.x * (PB_CH / 4) + t;
    int i1 = i0 + 256;
    bool v0 = i0 < nE4, v1 = i1 < nE4;
    iv4 d0 = {0,0,0,0}, s0 = {0,0,0,0}, d1 = {0,0,0,0}, s1 = {0,0,0,0};
    if (v0) { d0 = __builtin_nontemporal_load(&dst4[i0]); s0 = __builtin_nontemporal_load(&src4[i0]); }
    if (v1) { d1 = __builtin_nontemporal_load(&dst4[i1]); s1 = __builtin_nontemporal_load(&src4[i1]); }
    if (v0) {
        atomicAdd(&hist[slice_of(d0.x, M)][r], 1);
        atomicAdd(&hist[slice_of(d0.y, M)][r], 1);
        atomicAdd(&hist[slice_of(d0.z, M)][r], 1);
        atomicAdd(&hist[slice_of(d0.w, M)][r], 1);
    }
    if (v1) {
        atomicAdd(&hist[slice_of(d1.x, M)][r], 1);
        atomicAdd(&hist[slice_of(d1.y, M)][r], 1);
        atomicAdd(&hist[slice_of(d1.z, M)][r], 1);
        atomicAdd(&hist[slice_of(d1.w, M)][r], 1);
    }
    bool tailblk = (blockIdx.x == gridDim.x - 1) && (t == 0);
    if (tailblk) {
        for (int e = nE4 << 2; e < nE; ++e)
            atomicAdd(&hist[slice_of(dst[e], M)][0], 1);
    }
    __syncthreads();
    if (t < 8) {
        int tot = 0;
#pragma unroll
        for (int k = 0; k < 8; ++k) tot += hist[t][k];
        int g = tot ? atomicAdd(&binCur[t * 32], tot) : 0;
#pragma unroll
        for (int k = 0; k < 8; ++k) { base[t][k] = g; g += hist[t][k]; }
    }
    __syncthreads();
#define EMIT(dd, ss_) { int b = slice_of(dd, M); \
        int p = base[b][r] + atomicAdd(&cur[b][r], 1); \
        iv2 pr; pr.x = dd; pr.y = ss_; \
        __builtin_nontemporal_store(pr, &stg[p]); }
    if (v0) { EMIT(d0.x, s0.x) EMIT(d0.y, s0.y) EMIT(d0.z, s0.z) EMIT(d0.w, s0.w) }
    if (v1) { EMIT(d1.x, s1.x) EMIT(d1.y, s1.y) EMIT(d1.z, s1.z) EMIT(d1.w, s1.w) }
    if (tailblk) {
        for (int e = nE4 << 2; e < nE; ++e) {
            int dd = dst[e];
            int b = slice_of(dd, M);
            int p = base[b][0] + atomicAdd(&cur[b][0], 1);
            iv2 pr; pr.x = dd; pr.y = src[e];
            __builtin_nontemporal_store(pr, &stg[p]);
        }
    }
#undef EMIT
}

// ---------------------------------------------------------------------------
// Phase C1: per-slice degree count from own staging bin (rp slice L2-local)
// ---------------------------------------------------------------------------
__global__ void k_cnt2(const iv2* __restrict__ stg, const int* __restrict__ binStart,
                       int* __restrict__ rp)
{
    int s = blockIdx.x & 7;
    int b1 = binStart[s + 1];
    int idx = binStart[s] + (blockIdx.x >> 3) * blockDim.x + threadIdx.x;
    int step = (gridDim.x >> 3) * blockDim.x;
    for (; idx < b1; idx += step) {
        iv2 p = __builtin_nontemporal_load(&stg[idx]);
        atomicAdd(&rp[p.x], 1);
    }
}

// ---------------------------------------------------------------------------
// Phase C2: per-slice csr fill (cursor + csr slice L2-local)
// ---------------------------------------------------------------------------
__global__ void k_fill(const iv2* __restrict__ stg, const int* __restrict__ binStart,
                       int* __restrict__ cursor, int* __restrict__ csr)
{
    int s = blockIdx.x & 7;
    int b1 = binStart[s + 1];
    int idx = binStart[s] + (blockIdx.x >> 3) * blockDim.x + threadIdx.x;
    int step = (gridDim.x >> 3) * blockDim.x;
    for (; idx < b1; idx += step) {
        iv2 p = __builtin_nontemporal_load(&stg[idx]);
        int pos = atomicAdd(&cursor[p.x], 1);
        csr[pos] = p.y;
    }
}

// ---------------------------------------------------------------------------
// Fallback CSR build (used only if workspace too small for staging)
// ---------------------------------------------------------------------------
__global__ void k_count_fb(const int* __restrict__ dst, int* __restrict__ rp,
                           int n, int nE)
{
    int slice = blockIdx.x & 7;
    int lo = (int)(((long long)slice * n) >> 3);
    int hi = (int)(((long long)(slice + 1) * n) >> 3);
    int tid = (blockIdx.x >> 3) * blockDim.x + threadIdx.x;
    int stride = (gridDim.x >> 3) * blockDim.x;
    for (int e = tid; e < nE; e += stride) {
        int d = dst[e];
        if (d >= lo && d < hi) atomicAdd(&rp[d], 1);
    }
}
__global__ void k_scatter_fb(const int* __restrict__ src, const int* __restrict__ dst,
                             int* __restrict__ cursor, int* __restrict__ csr,
                             int n, int nE)
{
    int slice = blockIdx.x & 7;
    int lo = (int)(((long long)slice * n) >> 3);
    int hi = (int)(((long long)(slice + 1) * n) >> 3);
    int tid = (blockIdx.x >> 3) * blockDim.x + threadIdx.x;
    int stride = (gridDim.x >> 3) * blockDim.x;
    for (int e = tid; e < nE; e += stride) {
        int d = dst[e];
        if (d >= lo && d < hi) {
            int pos = atomicAdd(&cursor[d], 1);
            csr[pos] = src[e];
        }
    }
}

// ---------------------------------------------------------------------------
// Scan phase 1: per-chunk sums
// ---------------------------------------------------------------------------
__global__ void k_chunksum(const int* __restrict__ rp, int* __restrict__ csum, int n)
{
    __shared__ int red[4];
    int t = threadIdx.x;
    int base = blockIdx.x * SCH;
    int i = base + 2 * t;
    int s = 0;
    if (i < n)     s += rp[i];
    if (i + 1 < n) s += rp[i + 1];
#pragma unroll
    for (int m = 32; m >= 1; m >>= 1) s += __shfl_down(s, m, 64);
    if ((t & 63) == 0) red[t >> 6] = s;
    __syncthreads();
    if (t == 0) csum[blockIdx.x] = red[0] + red[1] + red[2] + red[3];
}

// ---------------------------------------------------------------------------
// Scan phase 2: exclusive scan of chunk sums (single small block)
// ---------------------------------------------------------------------------
__global__ void k_scanchunks(int* __restrict__ csum, int nchunks)
{
    __shared__ int ls[256];
    int t = threadIdx.x;
    int v = (t < nchunks) ? csum[t] : 0;
    ls[t] = v;
    __syncthreads();
#pragma unroll
    for (int off = 1; off < 256; off <<= 1) {
        int u = (t >= off) ? ls[t - off] : 0;
        __syncthreads();
        ls[t] += u;
        __syncthreads();
    }
    if (t < nchunks) csum[t] = (t == 0) ? 0 : ls[t - 1];
}

// ---------------------------------------------------------------------------
// Scan phase 3: per-chunk exclusive scan + chunk offset
// ---------------------------------------------------------------------------
__global__ void k_scanout(int* __restrict__ rp, const int* __restrict__ csum,
                          int* __restrict__ cursor, float* __restrict__ inv_cnt,
                          int n, int nE)
{
    __shared__ int ls[256];
    int t = threadIdx.x;
    int base = blockIdx.x * SCH;
    int i = base + 2 * t;
    int a0 = (i < n)     ? rp[i]     : 0;
    int a1 = (i + 1 < n) ? rp[i + 1] : 0;
    int tsum = a0 + a1;
    ls[t] = tsum;
    __syncthreads();
#pragma unroll
    for (int off = 1; off < 256; off <<= 1) {
        int u = (t >= off) ? ls[t - off] : 0;
        __syncthreads();
        ls[t] += u;
        __syncthreads();
    }
    int excl = csum[blockIdx.x] + ls[t] - tsum;
    if (i < n) {
        rp[i] = excl;
        cursor[i] = excl;
        inv_cnt[i] = 1.0f / fmaxf((float)a0, 1.0f);
    }
    if (i + 1 < n) {
        rp[i + 1] = excl + a0;
        cursor[i + 1] = excl + a0;
        inv_cnt[i + 1] = 1.0f / fmaxf((float)a1, 1.0f);
    }
    if (blockIdx.x == 0 && t == 0) rp[n] = nE;
}

// ---------------------------------------------------------------------------
// Layer 1: 16 lanes per node; shfl-reduce; BN+ReLU fused; bf16 out.
// ---------------------------------------------------------------------------
__global__ void k_l1g(const int* __restrict__ rp, const int* __restrict__ csr,
                      const float* __restrict__ inv_cnt, const float* __restrict__ x,
                      const float* __restrict__ W1l, const float* __restrict__ b1l,
                      const float* __restrict__ W1r,
                      const float* __restrict__ gam, const float* __restrict__ bet,
                      const float* __restrict__ mu,  const float* __restrict__ var,
                      bf16* __restrict__ hout, int n)
{
    __shared__ float sWl[16], sb[16], sWr[16], ssc[16], sbi[16];
    int t = threadIdx.x;
    if (t < 16) {
        sWl[t] = W1l[t]; sb[t] = b1l[t]; sWr[t] = W1r[t];
        float sc = gam[t] * rsqrtf(var[t] + EPS);
        ssc[t] = sc;
        sbi[t] = bet[t] - mu[t] * sc;
    }
    __syncthreads();
    int grp = t >> 4, f = t & 15;
    int i = blockIdx.x * 16 + grp;
    if (i >= n) return;
    int r0 = rp[i], r1 = rp[i + 1];
    float s = 0.0f;
    for (int k = r0 + f; k < r1; k += 16) s += x[csr[k]];
#pragma unroll
    for (int m = 8; m >= 1; m >>= 1) s += __shfl_xor(s, m, 64);
    float mean = s * inv_cnt[i];
    float xv = x[i];
    float v = fmaf(mean, sWl[f], sb[f]);
    v = fmaf(xv, sWr[f], v);
    v = fmaxf(fmaf(v, ssc[f], sbi[f]), 0.0f);
    hout[(size_t)i * 16 + f] = __float2bfloat16(v);
}

// ---------------------------------------------------------------------------
// Layers 2,3: fused gather-mean (16 bf16 feats) + 16->16 transform + ReLU.
// ---------------------------------------------------------------------------
__global__ void k_sage16(const int* __restrict__ rp, const int* __restrict__ csr,
                         const float* __restrict__ inv_cnt, const bf16* __restrict__ h,
                         const float* __restrict__ Wl, const float* __restrict__ bl,
                         const float* __restrict__ Wr,
                         bf16* __restrict__ hout, int n)
{
    __shared__ float sWlT[256], sWrT[256], sb[16];
    __shared__ float sA[16][17], sX[16][17];
    int t = threadIdx.x;
    {
        int j = t & 15, ii = t >> 4;
        sWlT[ii * 16 + j] = Wl[j * 16 + ii];
        sWrT[ii * 16 + j] = Wr[j * 16 + ii];
    }
    if (t < 16) sb[t] = bl[t];
    int grp = t >> 4, f = t & 15;
    int i = blockIdx.x * 16 + grp;
    bool valid = i < n;
    float acc = 0.0f, ic = 0.0f, hs = 0.0f;
    if (valid) {
        int r0 = rp[i], r1 = rp[i + 1];
#pragma unroll 4
        for (int k = r0; k < r1; ++k) {
            int nb = csr[k];
            acc += __bfloat162float(h[(size_t)nb * 16 + f]);
        }
        ic = inv_cnt[i];
        hs = __bfloat162float(h[(size_t)i * 16 + f]);
    }
    sA[grp][f] = acc * ic;
    sX[grp][f] = hs;
    __syncthreads();
    if (valid) {
        float o = sb[f];
#pragma unroll
        for (int ii = 0; ii < 16; ++ii) {
            o = fmaf(sA[grp][ii], sWlT[ii * 16 + f], o);
            o = fmaf(sX[grp][ii], sWrT[ii * 16 + f], o);
        }
        hout[(size_t)i * 16 + f] = __float2bfloat16(fmaxf(o, 0.0f));
    }
}

// ---------------------------------------------------------------------------
// Layer 4 + decoder + softmax, fused with gather.
// ---------------------------------------------------------------------------
__global__ void k_fin(const int* __restrict__ rp, const int* __restrict__ csr,
                      const float* __restrict__ inv_cnt, const bf16* __restrict__ h,
                      const float* __restrict__ W4l, const float* __restrict__ b4l,
                      const float* __restrict__ W4r,
                      const float* __restrict__ Wd1, const float* __restrict__ bd1,
                      const float* __restrict__ Wd2, const float* __restrict__ bd2,
                      float* __restrict__ out, int n)
{
    __shared__ float sW4lT[512], sW4rT[512], sb4[32];
    __shared__ float sWd1T[1024], sbd1[32], sWd2[64], sbd2[2];
    __shared__ float sA[16][17], sX[16][17], sH4[16][33];
    int t = threadIdx.x;
    for (int k = t; k < 512; k += 256) {
        int j = k >> 4, ii = k & 15;
        sW4lT[ii * 32 + j] = W4l[k];
        sW4rT[ii * 32 + j] = W4r[k];
    }
    for (int k = t; k < 1024; k += 256) {
        int j = k >> 5, ii = k & 31;
        sWd1T[ii * 32 + j] = Wd1[k];
    }
    if (t < 32) { sb4[t] = b4l[t]; sbd1[t] = bd1[t]; }
    if (t < 64) sWd2[t] = Wd2[t];
    if (t < 2)  sbd2[t] = bd2[t];
    int grp = t >> 4, f = t & 15;
    int i = blockIdx.x * 16 + grp;
    bool valid = i < n;
    float acc = 0.0f, ic = 0.0f, hs = 0.0f;
    if (valid) {
        int r0 = rp[i], r1 = rp[i + 1];
#pragma unroll 4
        for (int k = r0; k < r1; ++k) {
            int nb = csr[k];
            acc += __bfloat162float(h[(size_t)nb * 16 + f]);
        }
        ic = inv_cnt[i];
        hs = __bfloat162float(h[(size_t)i * 16 + f]);
    }
    sA[grp][f] = acc * ic;
    sX[grp][f] = hs;
    __syncthreads();
    float h4a = sb4[f], h4b = sb4[f + 16];
#pragma unroll
    for (int ii = 0; ii < 16; ++ii) {
        float a  = sA[grp][ii];
        float xx = sX[grp][ii];
        h4a = fmaf(a,  sW4lT[ii * 32 + f],      h4a);
        h4b = fmaf(a,  sW4lT[ii * 32 + f + 16], h4b);
        h4a = fmaf(xx, sW4rT[ii * 32 + f],      h4a);
        h4b = fmaf(xx, sW4rT[ii * 32 + f + 16], h4b);
    }
    sH4[grp][f] = h4a;
    sH4[grp][f + 16] = h4b;
    __syncthreads();
    float za = sbd1[f], zb = sbd1[f + 16];
#pragma unroll
    for (int k = 0; k < 32; ++k) {
        float hv = sH4[grp][k];
        za = fmaf(hv, sWd1T[k * 32 + f],      za);
        zb = fmaf(hv, sWd1T[k * 32 + f + 16], zb);
    }
    za = fmaxf(za, 0.0f);
    zb = fmaxf(zb, 0.0f);
    float o0 = za * sWd2[f]      + zb * sWd2[f + 16];
    float o1 = za * sWd2[32 + f] + zb * sWd2[32 + f + 16];
#pragma unroll
    for (int m = 8; m >= 1; m >>= 1) {
        o0 += __shfl_xor(o0, m, 64);
        o1 += __shfl_xor(o1, m, 64);
    }
    if (valid && f == 0) {
        o0 += sbd2[0]; o1 += sbd2[1];
        float mx = fmaxf(o0, o1);
        float e0 = expf(o0 - mx), e1 = expf(o1 - mx);
        float inv = 1.0f / (e0 + e1);
        out[(size_t)2 * i + 0] = e0 * inv;
        out[(size_t)2 * i + 1] = e1 * inv;
    }
}

// ---------------------------------------------------------------------------
extern "C" void kernel_launch(void* const* d_in, const int* in_sizes, int n_in,
                              void* d_out, int out_size, void* d_ws, size_t ws_size,
                              hipStream_t stream)
{
    const float* x  = (const float*)d_in[0];
    const int*   ei = (const int*)d_in[1];
    const int    N  = in_sizes[0];
    const int    E  = in_sizes[1] / 2;
    const int* src = ei;
    const int* dst = ei + E;

    const float* W1l = (const float*)d_in[2];
    const float* b1l = (const float*)d_in[3];
    const float* W1r = (const float*)d_in[4];
    const float* gam = (const float*)d_in[5];
    const float* bet = (const float*)d_in[6];
    const float* mu  = (const float*)d_in[7];
    const float* var = (const float*)d_in[8];
    const float* W2l = (const float*)d_in[9];
    const float* b2l = (const float*)d_in[10];
    const float* W2r = (const float*)d_in[11];
    const float* W3l = (const float*)d_in[12];
    const float* b3l = (const float*)d_in[13];
    const float* W3r = (const float*)d_in[14];
    const float* W4l = (const float*)d_in[15];
    const float* b4l = (const float*)d_in[16];
    const float* W4r = (const float*)d_in[17];
    const float* Wd1 = (const float*)d_in[18];
    const float* bd1 = (const float*)d_in[19];
    const float* Wd2 = (const float*)d_in[20];
    const float* bd2 = (const float*)d_in[21];

    char*  base = (char*)d_ws;
    size_t off  = 0;
    auto alloc = [&](size_t bytes) { size_t p = off; off += (bytes + 63) & ~(size_t)63; return p; };
    float* inv_cnt  = (float*)(base + alloc((size_t)N * 4));
    int*   rp       = (int*)  (base + alloc((size_t)(N + 1) * 4));
    int*   cursor   = (int*)  (base + alloc((size_t)N * 4));
    int*   csum     = (int*)  (base + alloc(256 * 4));
    int*   binCnt   = (int*)  (base + alloc(8 * 32 * 4));   // padded: 1 counter per line
    int*   binStart = (int*)  (base + alloc(16 * 4));
    int*   binCur   = (int*)  (base + alloc(8 * 32 * 4));
    int*   csr      = (int*)  (base + alloc((size_t)E * 4));
    // staging aliases hA/hB region (staging dead before first hA write)
    size_t regionOff = alloc((size_t)E * 8 > (size_t)N * 64 ? (size_t)E * 8 : (size_t)N * 64);
    iv2*   stg = (iv2*) (base + regionOff);
    bf16*  hA  = (bf16*)(base + regionOff);
    bf16*  hB  = hA + (size_t)N * 16;
    bool radix_ok = (off <= ws_size);

    unsigned ss = (unsigned)((N + 7) / 8);
    unsigned M  = (unsigned)(((1ULL << 32) + ss - 1) / ss);

    int nbN16   = (N + 15) / 16;
    int nchunks = (N + SCH - 1) / SCH;      // 196 for N=100000 (<=256 required)

    hipMemsetAsync(rp, 0, (size_t)(N + 1) * sizeof(int), stream);

    if (radix_ok) {
        hipMemsetAsync(binCnt, 0, 8 * 32 * sizeof(int), stream);
        int nbPairs = (E + PB_CH - 1) / PB_CH;
        k_hist<<<2048, 256, 0, stream>>>(dst, binCnt, M, E);
        k_binscan<<<1, 64, 0, stream>>>(binCnt, binStart, binCur);
        k_pairs<<<nbPairs, 256, 0, stream>>>(src, dst, binCur, stg, M, E);
        k_cnt2<<<2048, 256, 0, stream>>>(stg, binStart, rp);
        k_chunksum<<<nchunks, 256, 0, stream>>>(rp, csum, N);
        k_scanchunks<<<1, 256, 0, stream>>>(csum, nchunks);
        k_scanout<<<nchunks, 256, 0, stream>>>(rp, csum, cursor, inv_cnt, N, E);
        k_fill<<<2048, 256, 0, stream>>>(stg, binStart, cursor, csr);
    } else {
        int nbEdge = 8 * 256;
        k_count_fb<<<nbEdge, 256, 0, stream>>>(dst, rp, N, E);
        k_chunksum<<<nchunks, 256, 0, stream>>>(rp, csum, N);
        k_scanchunks<<<1, 256, 0, stream>>>(csum, nchunks);
        k_scanout<<<nchunks, 256, 0, stream>>>(rp, csum, cursor, inv_cnt, N, E);
        k_scatter_fb<<<nbEdge, 256, 0, stream>>>(src, dst, cursor, csr, N, E);
    }

    // --- layers ---
    k_l1g<<<nbN16, 256, 0, stream>>>(rp, csr, inv_cnt, x, W1l, b1l, W1r,
                                     gam, bet, mu, var, hA, N);
    k_sage16<<<nbN16, 256, 0, stream>>>(rp, csr, inv_cnt, hA, W2l, b2l, W2r, hB, N);
    k_sage16<<<nbN16, 256, 0, stream>>>(rp, csr, inv_cnt, hB, W3l, b3l, W3r, hA, N);
    k_fin<<<nbN16, 256, 0, stream>>>(rp, csr, inv_cnt, hA, W4l, b4l, W4r,
                                     Wd1, bd1, Wd2, bd2, (float*)d_out, N);
}